// Round 1
// baseline (734.877 us; speedup 1.0000x reference)
//
#include <hip/hip_runtime.h>
#include <stdint.h>

#define NROWS 1024
#define CDIM  4096
#define KDIM  16384
#define SIDE  128

typedef __attribute__((ext_vector_type(8))) short short8;
typedef __attribute__((ext_vector_type(4))) float f32x4;

static __device__ __forceinline__ unsigned short f2bf(float f) {
  unsigned u = __float_as_uint(f);
  u += 0x7fffu + ((u >> 16) & 1u);   // round-to-nearest-even
  return (unsigned short)(u >> 16);
}
static __device__ __forceinline__ float bf2f(unsigned short h) {
  return __uint_as_float(((unsigned)h) << 16);
}

#define GLOAD_LDS16(g, l)                                                     \
  __builtin_amdgcn_global_load_lds(                                           \
      (const __attribute__((address_space(1))) void*)(g),                     \
      (__attribute__((address_space(3))) void*)(l), 16, 0, 0)

// XOR-swizzle within a 64-byte LDS row: chunk ^= (row & 3). Involution;
// preserves 16B alignment and row index (bits >=6 untouched).
#define SWZ(o) ((o) ^ (((o) >> 2) & 48))

// ---------- weights: f32 [c][k] -> bf16 hi/lo transposed [k][c] ----------
__global__ __launch_bounds__(256) void k_wconv(const float* __restrict__ w,
                                               unsigned short* __restrict__ whT,
                                               unsigned short* __restrict__ wlT) {
  __shared__ float T[64][65];
  const int k0 = blockIdx.x * 64, c0 = blockIdx.y * 64;
  const int t = threadIdx.x;
#pragma unroll
  for (int i = 0; i < 4; i++) {
    int e = i * 1024 + t * 4;
    int cr = e >> 6, kc = e & 63;
    float4 v = *(const float4*)(w + (size_t)(c0 + cr) * KDIM + k0 + kc);
    T[cr][kc] = v.x; T[cr][kc + 1] = v.y; T[cr][kc + 2] = v.z; T[cr][kc + 3] = v.w;
  }
  __syncthreads();
#pragma unroll
  for (int i = 0; i < 4; i++) {
    int e = i * 1024 + t * 4;
    int kr = e >> 6, cc = e & 63;
    ushort4 hv, lv;
    float f0 = T[cc + 0][kr], f1 = T[cc + 1][kr];
    float f2 = T[cc + 2][kr], f3 = T[cc + 3][kr];
    hv.x = f2bf(f0); lv.x = f2bf(f0 - bf2f(hv.x));
    hv.y = f2bf(f1); lv.y = f2bf(f1 - bf2f(hv.y));
    hv.z = f2bf(f2); lv.z = f2bf(f2 - bf2f(hv.z));
    hv.w = f2bf(f3); lv.w = f2bf(f3 - bf2f(hv.w));
    size_t off = (size_t)(k0 + kr) * CDIM + c0 + cc;
    *(ushort4*)(whT + off) = hv;
    *(ushort4*)(wlT + off) = lv;
  }
}

// ---------- x: f32 [n][c] -> bf16 hi/lo (same layout) ----------
__global__ __launch_bounds__(256) void k_xconv(const float* __restrict__ x,
                                               unsigned short* __restrict__ xh,
                                               unsigned short* __restrict__ xl) {
  size_t i = ((size_t)blockIdx.x * 256 + threadIdx.x) * 4;
  float4 v = *(const float4*)(x + i);
  ushort4 hv, lv;
  hv.x = f2bf(v.x); lv.x = f2bf(v.x - bf2f(hv.x));
  hv.y = f2bf(v.y); lv.y = f2bf(v.y - bf2f(hv.y));
  hv.z = f2bf(v.z); lv.z = f2bf(v.z - bf2f(hv.z));
  hv.w = f2bf(v.w); lv.w = f2bf(v.w - bf2f(hv.w));
  *(ushort4*)(xh + i) = hv;
  *(ushort4*)(xl + i) = lv;
}

// ---------- x2[n] = sum_c x^2 ----------
__global__ void k_x2(const float* __restrict__ x, float* __restrict__ x2) {
  const int n = blockIdx.x, l = threadIdx.x;  // 64 threads
  const float* row = x + (size_t)n * CDIM;
  float s = 0.f;
#pragma unroll 4
  for (int i = 0; i < 16; i++) {
    float4 v = *(const float4*)(row + (i * 64 + l) * 4);
    s += v.x * v.x + v.y * v.y + v.z * v.z + v.w * v.w;
  }
#pragma unroll
  for (int off = 32; off > 0; off >>= 1) s += __shfl_down(s, off);
  if (l == 0) x2[n] = s;
}

// ---------- w2[k] = sum_c w^2 (partial chunks + atomicAdd) ----------
__global__ __launch_bounds__(256) void k_w2(const float* __restrict__ w,
                                            float* __restrict__ w2) {
  const int k = blockIdx.x * 256 + threadIdx.x;
  const int c0 = blockIdx.y * 512;
  float s = 0.f;
  for (int c = c0; c < c0 + 512; c++) {
    float v = w[(size_t)c * KDIM + k];
    s += v * v;
  }
  atomicAdd(&w2[k], s);
}

// ---------- main MFMA GEMM: norms2 -> out ----------
__global__ __launch_bounds__(256) void k_gemm(
    const unsigned short* __restrict__ xh, const unsigned short* __restrict__ xl,
    const unsigned short* __restrict__ whT, const unsigned short* __restrict__ wlT,
    const float* __restrict__ x2, const float* __restrict__ w2,
    float* __restrict__ out) {
  __shared__ alignas(128) char smem[32768];
  char* const Ah = smem;
  char* const Al = smem + 8192;
  char* const Bh = smem + 16384;
  char* const Bl = smem + 24576;
  const int t = threadIdx.x;
  const int m0 = blockIdx.x * 128, n0 = blockIdx.y * 128;
  const int lane = t & 63;
  const int wr = ((t >> 7) & 1) * 64;  // wave row quadrant
  const int wc = ((t >> 6) & 1) * 64;  // wave col quadrant

  // staging geometry: thread t, round i fills linear LDS chunk o_lin; the
  // data that belongs there is logical chunk SWZ(o_lin) (rule #21: inverse-
  // swizzled global source + linear LDS dest + swizzled reads).
  int rowS[2], cbS[2];
  uint32_t loff[2];
#pragma unroll
  for (int i = 0; i < 2; i++) {
    int o_lin = (i * 256 + t) * 16;
    int o_log = SWZ(o_lin);
    rowS[i] = o_log >> 6;          // tile row (0..127)
    cbS[i]  = (o_log & 63) >> 1;   // element offset in row (0..31)
    loff[i] = i * 4096 + (t >> 6) * 1024;  // wave-uniform LDS base
  }

  f32x4 acc[4][4];
#pragma unroll
  for (int m = 0; m < 4; m++)
#pragma unroll
    for (int n = 0; n < 4; n++) acc[m][n] = (f32x4){0.f, 0.f, 0.f, 0.f};

  for (int c0 = 0; c0 < CDIM; c0 += 32) {
#pragma unroll
    for (int i = 0; i < 2; i++) {
      size_t ga = (size_t)(m0 + rowS[i]) * CDIM + c0 + cbS[i];
      size_t gb = (size_t)(n0 + rowS[i]) * CDIM + c0 + cbS[i];
      GLOAD_LDS16(xh + ga, Ah + loff[i]);
      GLOAD_LDS16(xl + ga, Al + loff[i]);
      GLOAD_LDS16(whT + gb, Bh + loff[i]);
      GLOAD_LDS16(wlT + gb, Bl + loff[i]);
    }
    __syncthreads();  // compiler drains vmcnt before s_barrier

    short8 a_h[4], a_l[4], b_h[4], b_l[4];
    const int cby = (lane >> 4) * 16;  // k-group byte offset
    const int rlo = lane & 15;
#pragma unroll
    for (int m = 0; m < 4; m++) {
      int p = SWZ((wr + m * 16 + rlo) * 64 + cby);
      a_h[m] = *(const short8*)(Ah + p);
      a_l[m] = *(const short8*)(Al + p);
    }
#pragma unroll
    for (int n = 0; n < 4; n++) {
      int p = SWZ((wc + n * 16 + rlo) * 64 + cby);
      b_h[n] = *(const short8*)(Bh + p);
      b_l[n] = *(const short8*)(Bl + p);
    }
#pragma unroll
    for (int m = 0; m < 4; m++)
#pragma unroll
      for (int n = 0; n < 4; n++) {
        acc[m][n] = __builtin_amdgcn_mfma_f32_16x16x32_bf16(a_h[m], b_h[n], acc[m][n], 0, 0, 0);
        acc[m][n] = __builtin_amdgcn_mfma_f32_16x16x32_bf16(a_h[m], b_l[n], acc[m][n], 0, 0, 0);
        acc[m][n] = __builtin_amdgcn_mfma_f32_16x16x32_bf16(a_l[m], b_h[n], acc[m][n], 0, 0, 0);
      }
    __syncthreads();
  }

  // epilogue: norms2 = max(x2 + w2 - 2*xw, 0)
  float w2v[4];
#pragma unroll
  for (int n = 0; n < 4; n++) w2v[n] = w2[n0 + wc + n * 16 + (lane & 15)];
#pragma unroll
  for (int m = 0; m < 4; m++) {
#pragma unroll
    for (int j = 0; j < 4; j++) {
      int row = m0 + wr + m * 16 + (lane >> 4) * 4 + j;
      float xr = x2[row];
      float* orow = out + (size_t)row * KDIM;
#pragma unroll
      for (int n = 0; n < 4; n++) {
        int col = n0 + wc + n * 16 + (lane & 15);
        float v = xr + w2v[n] - 2.0f * acc[m][n][j];
        orow[col] = v < 0.f ? 0.f : v;
      }
    }
  }
}

// ---------- fallback fp32 GEMM (direct sum of (w-x)^2), used only if ws too small ----------
__global__ __launch_bounds__(256) void k_fb(const float* __restrict__ x,
                                            const float* __restrict__ w,
                                            float* __restrict__ out) {
  __shared__ float xs[16][65];
  __shared__ float wsm[16][65];
  const int t = threadIdx.x;
  const int n0 = blockIdx.x * 64, k0 = blockIdx.y * 64;
  const int tx = t & 15, ty = t >> 4;
  float acc[4][4];
#pragma unroll
  for (int a = 0; a < 4; a++)
#pragma unroll
    for (int b = 0; b < 4; b++) acc[a][b] = 0.f;
  for (int c0 = 0; c0 < CDIM; c0 += 16) {
#pragma unroll
    for (int i = 0; i < 4; i++) {
      int e = i * 256 + t;
      int nl = e >> 4, cl = e & 15;
      xs[cl][nl] = x[(size_t)(n0 + nl) * CDIM + c0 + cl];
    }
#pragma unroll
    for (int i = 0; i < 4; i++) {
      int e = i * 256 + t;
      int cl = e >> 6, kl = e & 63;
      wsm[cl][kl] = w[(size_t)(c0 + cl) * KDIM + k0 + kl];
    }
    __syncthreads();
#pragma unroll
    for (int c = 0; c < 16; c++)
#pragma unroll
      for (int a = 0; a < 4; a++) {
        float xa = xs[c][ty * 4 + a];
#pragma unroll
        for (int b = 0; b < 4; b++) {
          float d = wsm[c][tx * 4 + b] - xa;
          acc[a][b] += d * d;
        }
      }
    __syncthreads();
  }
#pragma unroll
  for (int a = 0; a < 4; a++)
#pragma unroll
    for (int b = 0; b < 4; b++)
      out[(size_t)(n0 + ty * 4 + a) * KDIM + k0 + tx * 4 + b] = acc[a][b];
}

// ---------- per-row: argmin -> separable RBF -> scale in place ----------
__global__ __launch_bounds__(256) void k_row(float* __restrict__ out,
                                             const float* __restrict__ stdp) {
  const int n = blockIdx.x, t = threadIdx.x;
  __shared__ alignas(16) float er[SIDE];
  __shared__ alignas(16) float ec[SIDE];
  __shared__ float rv[4];
  __shared__ int ri[4];
  __shared__ float s_inv;
  __shared__ int s_bmu;
  float* row = out + (size_t)n * KDIM;

  float bv = 3.4e38f;
  int bi = 0;
#pragma unroll 4
  for (int i = 0; i < 16; i++) {
    int k = (t + i * 256) * 4;
    float4 v = *(const float4*)(row + k);
    if (v.x < bv) { bv = v.x; bi = k; }
    if (v.y < bv) { bv = v.y; bi = k + 1; }
    if (v.z < bv) { bv = v.z; bi = k + 2; }
    if (v.w < bv) { bv = v.w; bi = k + 3; }
  }
#pragma unroll
  for (int off = 32; off > 0; off >>= 1) {
    float ov = __shfl_down(bv, off);
    int oi = __shfl_down(bi, off);
    if (ov < bv || (ov == bv && oi < bi)) { bv = ov; bi = oi; }
  }
  if ((t & 63) == 0) { rv[t >> 6] = bv; ri[t >> 6] = bi; }
  __syncthreads();
  if (t == 0) {
    for (int i = 1; i < 4; i++)
      if (rv[i] < bv || (rv[i] == bv && ri[i] < bi)) { bv = rv[i]; bi = ri[i]; }
    s_bmu = bi;
  }
  __syncthreads();
  const int bmu = s_bmu;
  const float sd = stdp[0];
  const float inv2s2 = -0.5f / (sd * sd);
  const float rr = (float)(bmu >> 7), ccol = (float)(bmu & 127);
  if (t < 128) {
    float d = (float)t - rr;
    er[t] = expf(d * d * inv2s2);
  } else {
    int j = t - 128;
    float d = (float)j - ccol;
    ec[j] = expf(d * d * inv2s2);
  }
  __syncthreads();
  if (t == 0) {
    float Sr = 0.f, Sc = 0.f;
    for (int i = 0; i < SIDE; i++) { Sr += er[i]; Sc += ec[i]; }
    s_inv = 1.0f / (Sr * Sc);
  }
  __syncthreads();
  const float inv = s_inv;
#pragma unroll 4
  for (int i = 0; i < 16; i++) {
    int k = (t + i * 256) * 4;
    float4 v = *(const float4*)(row + k);
    float e_r = er[k >> 7] * inv;
    const float4 e4 = *(const float4*)(&ec[k & 127]);
    v.x *= e_r * e4.x;
    v.y *= e_r * e4.y;
    v.z *= e_r * e4.z;
    v.w *= e_r * e4.w;
    *(float4*)(row + k) = v;
  }
}

extern "C" void kernel_launch(void* const* d_in, const int* in_sizes, int n_in,
                              void* d_out, int out_size, void* d_ws, size_t ws_size,
                              hipStream_t stream) {
  (void)in_sizes; (void)n_in; (void)out_size;
  const float* x = (const float*)d_in[0];
  const float* w = (const float*)d_in[1];
  const float* stdp = (const float*)d_in[2];
  float* out = (float*)d_out;

  const size_t sz_wT = (size_t)KDIM * CDIM * sizeof(unsigned short);  // 128 MiB each
  const size_t sz_x  = (size_t)NROWS * CDIM * sizeof(unsigned short); // 8 MiB each
  const size_t need = 2 * sz_wT + 2 * sz_x + (size_t)NROWS * 4 + (size_t)KDIM * 4;

  if (ws_size >= need) {
    char* p = (char*)d_ws;
    unsigned short* whT = (unsigned short*)p; p += sz_wT;
    unsigned short* wlT = (unsigned short*)p; p += sz_wT;
    unsigned short* xh  = (unsigned short*)p; p += sz_x;
    unsigned short* xl  = (unsigned short*)p; p += sz_x;
    float* x2 = (float*)p; p += (size_t)NROWS * 4;
    float* w2 = (float*)p;

    hipMemsetAsync(w2, 0, (size_t)KDIM * 4, stream);
    k_wconv<<<dim3(KDIM / 64, CDIM / 64), 256, 0, stream>>>(w, whT, wlT);
    k_xconv<<<(NROWS * CDIM) / 1024, 256, 0, stream>>>(x, xh, xl);
    k_x2<<<NROWS, 64, 0, stream>>>(x, x2);
    k_w2<<<dim3(KDIM / 256, 8), 256, 0, stream>>>(w, w2);
    k_gemm<<<dim3(NROWS / 128, KDIM / 128), 256, 0, stream>>>(xh, xl, whT, wlT, x2, w2, out);
  } else {
    k_fb<<<dim3(NROWS / 64, KDIM / 64), 256, 0, stream>>>(x, w, out);
  }
  k_row<<<NROWS, 256, 0, stream>>>(out, stdp);
}

// Round 2
// 655.169 us; speedup vs baseline: 1.1217x; 1.1217x over previous
//
#include <hip/hip_runtime.h>
#include <stdint.h>

#define NROWS 1024
#define CDIM  4096
#define KDIM  16384
#define SIDE  128

typedef __attribute__((ext_vector_type(8))) short short8;
typedef __attribute__((ext_vector_type(4))) float f32x4;

static __device__ __forceinline__ unsigned short f2bf(float f) {
  unsigned u = __float_as_uint(f);
  u += 0x7fffu + ((u >> 16) & 1u);   // round-to-nearest-even
  return (unsigned short)(u >> 16);
}
static __device__ __forceinline__ float bf2f(unsigned short h) {
  return __uint_as_float(((unsigned)h) << 16);
}

#define GLOAD_LDS16(g, l)                                                     \
  __builtin_amdgcn_global_load_lds(                                           \
      (const __attribute__((address_space(1))) void*)(g),                     \
      (__attribute__((address_space(3))) void*)(l), 16, 0, 0)

// XOR-swizzle: 16B-chunk bits [5:4] ^= row bits (row>>1)&3 (byte bits [8:7]).
// Bank-quad = (row&1)*4 + (chunk ^ ((row>>1)&3)) -> bijective over 8 quads
// for 8 consecutive rows; a 64-lane ds_read_b128 at fixed chunk over 16 rows
// is perfectly bank-uniform. Involution; preserves 16B alignment and row.
#define SWZ(o) ((o) ^ (((o) >> 3) & 48))

// ---------- weights: f32 [c][k] -> bf16 hi/lo transposed [k][c]; fused w2 ----
__global__ __launch_bounds__(256) void k_wconv(const float* __restrict__ w,
                                               unsigned short* __restrict__ whT,
                                               unsigned short* __restrict__ wlT,
                                               float* __restrict__ w2) {
  __shared__ float T[64][65];
  const int k0 = blockIdx.x * 64, c0 = blockIdx.y * 64;
  const int t = threadIdx.x;
#pragma unroll
  for (int i = 0; i < 4; i++) {
    int e = i * 1024 + t * 4;
    int cr = e >> 6, kc = e & 63;
    float4 v = *(const float4*)(w + (size_t)(c0 + cr) * KDIM + k0 + kc);
    T[cr][kc] = v.x; T[cr][kc + 1] = v.y; T[cr][kc + 2] = v.z; T[cr][kc + 3] = v.w;
  }
  __syncthreads();
#pragma unroll
  for (int i = 0; i < 4; i++) {
    int e = i * 1024 + t * 4;
    int kr = e >> 6, cc = e & 63;
    ushort4 hv, lv;
    float f0 = T[cc + 0][kr], f1 = T[cc + 1][kr];
    float f2 = T[cc + 2][kr], f3 = T[cc + 3][kr];
    hv.x = f2bf(f0); lv.x = f2bf(f0 - bf2f(hv.x));
    hv.y = f2bf(f1); lv.y = f2bf(f1 - bf2f(hv.y));
    hv.z = f2bf(f2); lv.z = f2bf(f2 - bf2f(hv.z));
    hv.w = f2bf(f3); lv.w = f2bf(f3 - bf2f(hv.w));
    size_t off = (size_t)(k0 + kr) * CDIM + c0 + cc;
    *(ushort4*)(whT + off) = hv;
    *(ushort4*)(wlT + off) = lv;
    // fused w2: threads with the same kr are 16 consecutive lanes
    float s = f0 * f0 + f1 * f1 + f2 * f2 + f3 * f3;
#pragma unroll
    for (int off2 = 8; off2 > 0; off2 >>= 1) s += __shfl_down(s, off2);
    if ((t & 15) == 0) atomicAdd(&w2[k0 + kr], s);
  }
}

// ---------- x: f32 [n][c] -> bf16 hi/lo (same layout) ----------
__global__ __launch_bounds__(256) void k_xconv(const float* __restrict__ x,
                                               unsigned short* __restrict__ xh,
                                               unsigned short* __restrict__ xl) {
  size_t i = ((size_t)blockIdx.x * 256 + threadIdx.x) * 4;
  float4 v = *(const float4*)(x + i);
  ushort4 hv, lv;
  hv.x = f2bf(v.x); lv.x = f2bf(v.x - bf2f(hv.x));
  hv.y = f2bf(v.y); lv.y = f2bf(v.y - bf2f(hv.y));
  hv.z = f2bf(v.z); lv.z = f2bf(v.z - bf2f(hv.z));
  hv.w = f2bf(v.w); lv.w = f2bf(v.w - bf2f(hv.w));
  *(ushort4*)(xh + i) = hv;
  *(ushort4*)(xl + i) = lv;
}

// ---------- x2[n] = sum_c x^2 ----------
__global__ void k_x2(const float* __restrict__ x, float* __restrict__ x2) {
  const int n = blockIdx.x, l = threadIdx.x;  // 64 threads
  const float* row = x + (size_t)n * CDIM;
  float s = 0.f;
#pragma unroll 4
  for (int i = 0; i < 16; i++) {
    float4 v = *(const float4*)(row + (i * 64 + l) * 4);
    s += v.x * v.x + v.y * v.y + v.z * v.z + v.w * v.w;
  }
#pragma unroll
  for (int off = 32; off > 0; off >>= 1) s += __shfl_down(s, off);
  if (l == 0) x2[n] = s;
}

// ---------- main MFMA GEMM: norms2 -> out ----------
// BM=256, BN=128, BK=32; 512 threads = 8 waves as 4(M) x 2(N);
// per-wave 64x64 output = acc[4][4] of 16x16x32 fragments, 3 MFMA per (m,n).
__global__ __launch_bounds__(512, 3) void k_gemm(
    const unsigned short* __restrict__ xh, const unsigned short* __restrict__ xl,
    const unsigned short* __restrict__ whT, const unsigned short* __restrict__ wlT,
    const float* __restrict__ x2, const float* __restrict__ w2,
    float* __restrict__ out) {
  __shared__ alignas(128) char smem[49152];
  char* const Ah = smem;            // 16 KB: 256 rows x 64B
  char* const Al = smem + 16384;    // 16 KB
  char* const Bh = smem + 32768;    // 8 KB: 128 rows x 64B
  char* const Bl = smem + 40960;    // 8 KB
  const int t = threadIdx.x;
  const int m0 = blockIdx.x * 256, n0 = blockIdx.y * 128;
  const int lane = t & 63, wid = t >> 6;
  const int wr = (wid >> 1) * 64;   // wave row quadrant: 0,64,128,192
  const int wc = (wid & 1) * 64;    // wave col half: 0,64

  // staging geometry (rule #21): linear LDS dest chunk o_lin holds logical
  // chunk SWZ(o_lin) -> fetch that chunk's global data into it.
  int rowA[2], cbA[2];
  uint32_t loffA[2];
#pragma unroll
  for (int i = 0; i < 2; i++) {
    int o_lin = (i * 512 + t) * 16;
    int o_log = SWZ(o_lin);
    rowA[i] = o_log >> 6;
    cbA[i] = (o_log & 63) >> 1;
    loffA[i] = i * 8192 + wid * 1024;  // wave-uniform LDS base
  }
  const int o_logB = SWZ(t * 16);
  const int rowB = o_logB >> 6;
  const int cbB = (o_logB & 63) >> 1;
  const uint32_t loffB = wid * 1024;

  f32x4 acc[4][4];
#pragma unroll
  for (int m = 0; m < 4; m++)
#pragma unroll
    for (int n = 0; n < 4; n++) acc[m][n] = (f32x4){0.f, 0.f, 0.f, 0.f};

  for (int c0 = 0; c0 < CDIM; c0 += 32) {
#pragma unroll
    for (int i = 0; i < 2; i++) {
      size_t ga = (size_t)(m0 + rowA[i]) * CDIM + c0 + cbA[i];
      GLOAD_LDS16(xh + ga, Ah + loffA[i]);
      GLOAD_LDS16(xl + ga, Al + loffA[i]);
    }
    {
      size_t gb = (size_t)(n0 + rowB) * CDIM + c0 + cbB;
      GLOAD_LDS16(whT + gb, Bh + loffB);
      GLOAD_LDS16(wlT + gb, Bl + loffB);
    }
    __syncthreads();  // drains vmcnt before s_barrier

    const int cby = (lane >> 4) * 16;  // k-group byte offset
    const int rlo = lane & 15;
    short8 b_h[4], b_l[4];
#pragma unroll
    for (int n = 0; n < 4; n++) {
      int p = SWZ((wc + n * 16 + rlo) * 64 + cby);
      b_h[n] = *(const short8*)(Bh + p);
      b_l[n] = *(const short8*)(Bl + p);
    }
#pragma unroll
    for (int m = 0; m < 4; m++) {
      int p = SWZ((wr + m * 16 + rlo) * 64 + cby);
      short8 ah = *(const short8*)(Ah + p);
      short8 al = *(const short8*)(Al + p);
#pragma unroll
      for (int n = 0; n < 4; n++) {
        acc[m][n] = __builtin_amdgcn_mfma_f32_16x16x32_bf16(ah, b_h[n], acc[m][n], 0, 0, 0);
        acc[m][n] = __builtin_amdgcn_mfma_f32_16x16x32_bf16(ah, b_l[n], acc[m][n], 0, 0, 0);
        acc[m][n] = __builtin_amdgcn_mfma_f32_16x16x32_bf16(al, b_h[n], acc[m][n], 0, 0, 0);
      }
    }
    __syncthreads();
  }

  // epilogue: norms2 = max(x2 + w2 - 2*xw, 0)
  float w2v[4];
#pragma unroll
  for (int n = 0; n < 4; n++) w2v[n] = w2[n0 + wc + n * 16 + (lane & 15)];
#pragma unroll
  for (int m = 0; m < 4; m++) {
#pragma unroll
    for (int j = 0; j < 4; j++) {
      int row = m0 + wr + m * 16 + (lane >> 4) * 4 + j;
      float xr = x2[row];
      float* orow = out + (size_t)row * KDIM;
#pragma unroll
      for (int n = 0; n < 4; n++) {
        int col = n0 + wc + n * 16 + (lane & 15);
        float v = xr + w2v[n] - 2.0f * acc[m][n][j];
        orow[col] = v < 0.f ? 0.f : v;
      }
    }
  }
}

// ---------- fallback fp32 GEMM (direct sum of (w-x)^2), used only if ws too small ----------
__global__ __launch_bounds__(256) void k_fb(const float* __restrict__ x,
                                            const float* __restrict__ w,
                                            float* __restrict__ out) {
  __shared__ float xs[16][65];
  __shared__ float wsm[16][65];
  const int t = threadIdx.x;
  const int n0 = blockIdx.x * 64, k0 = blockIdx.y * 64;
  const int tx = t & 15, ty = t >> 4;
  float acc[4][4];
#pragma unroll
  for (int a = 0; a < 4; a++)
#pragma unroll
    for (int b = 0; b < 4; b++) acc[a][b] = 0.f;
  for (int c0 = 0; c0 < CDIM; c0 += 16) {
#pragma unroll
    for (int i = 0; i < 4; i++) {
      int e = i * 256 + t;
      int nl = e >> 4, cl = e & 15;
      xs[cl][nl] = x[(size_t)(n0 + nl) * CDIM + c0 + cl];
    }
#pragma unroll
    for (int i = 0; i < 4; i++) {
      int e = i * 256 + t;
      int cl = e >> 6, kl = e & 63;
      wsm[cl][kl] = w[(size_t)(c0 + cl) * KDIM + k0 + kl];
    }
    __syncthreads();
#pragma unroll
    for (int c = 0; c < 16; c++)
#pragma unroll
      for (int a = 0; a < 4; a++) {
        float xa = xs[c][ty * 4 + a];
#pragma unroll
        for (int b = 0; b < 4; b++) {
          float d = wsm[c][tx * 4 + b] - xa;
          acc[a][b] += d * d;
        }
      }
    __syncthreads();
  }
#pragma unroll
  for (int a = 0; a < 4; a++)
#pragma unroll
    for (int b = 0; b < 4; b++)
      out[(size_t)(n0 + ty * 4 + a) * KDIM + k0 + tx * 4 + b] = acc[a][b];
}

// ---------- per-row: argmin -> separable RBF -> scale in place ----------
__global__ __launch_bounds__(256) void k_row(float* __restrict__ out,
                                             const float* __restrict__ stdp) {
  const int n = blockIdx.x, t = threadIdx.x;
  __shared__ alignas(16) float er[SIDE];
  __shared__ alignas(16) float ec[SIDE];
  __shared__ float rv[4];
  __shared__ int ri[4];
  __shared__ float s_inv;
  __shared__ int s_bmu;
  float* row = out + (size_t)n * KDIM;

  float bv = 3.4e38f;
  int bi = 0;
#pragma unroll 4
  for (int i = 0; i < 16; i++) {
    int k = (t + i * 256) * 4;
    float4 v = *(const float4*)(row + k);
    if (v.x < bv) { bv = v.x; bi = k; }
    if (v.y < bv) { bv = v.y; bi = k + 1; }
    if (v.z < bv) { bv = v.z; bi = k + 2; }
    if (v.w < bv) { bv = v.w; bi = k + 3; }
  }
#pragma unroll
  for (int off = 32; off > 0; off >>= 1) {
    float ov = __shfl_down(bv, off);
    int oi = __shfl_down(bi, off);
    if (ov < bv || (ov == bv && oi < bi)) { bv = ov; bi = oi; }
  }
  if ((t & 63) == 0) { rv[t >> 6] = bv; ri[t >> 6] = bi; }
  __syncthreads();
  if (t == 0) {
    for (int i = 1; i < 4; i++)
      if (rv[i] < bv || (rv[i] == bv && ri[i] < bi)) { bv = rv[i]; bi = ri[i]; }
    s_bmu = bi;
  }
  __syncthreads();
  const int bmu = s_bmu;
  const float sd = stdp[0];
  const float inv2s2 = -0.5f / (sd * sd);
  const float rr = (float)(bmu >> 7), ccol = (float)(bmu & 127);
  if (t < 128) {
    float d = (float)t - rr;
    er[t] = expf(d * d * inv2s2);
  } else {
    int j = t - 128;
    float d = (float)j - ccol;
    ec[j] = expf(d * d * inv2s2);
  }
  __syncthreads();
  if (t == 0) {
    float Sr = 0.f, Sc = 0.f;
    for (int i = 0; i < SIDE; i++) { Sr += er[i]; Sc += ec[i]; }
    s_inv = 1.0f / (Sr * Sc);
  }
  __syncthreads();
  const float inv = s_inv;
#pragma unroll 4
  for (int i = 0; i < 16; i++) {
    int k = (t + i * 256) * 4;
    float4 v = *(const float4*)(row + k);
    float e_r = er[k >> 7] * inv;
    const float4 e4 = *(const float4*)(&ec[k & 127]);
    v.x *= e_r * e4.x;
    v.y *= e_r * e4.y;
    v.z *= e_r * e4.z;
    v.w *= e_r * e4.w;
    *(float4*)(row + k) = v;
  }
}

extern "C" void kernel_launch(void* const* d_in, const int* in_sizes, int n_in,
                              void* d_out, int out_size, void* d_ws, size_t ws_size,
                              hipStream_t stream) {
  (void)in_sizes; (void)n_in; (void)out_size;
  const float* x = (const float*)d_in[0];
  const float* w = (const float*)d_in[1];
  const float* stdp = (const float*)d_in[2];
  float* out = (float*)d_out;

  const size_t sz_wT = (size_t)KDIM * CDIM * sizeof(unsigned short);  // 128 MiB each
  const size_t sz_x  = (size_t)NROWS * CDIM * sizeof(unsigned short); // 8 MiB each
  const size_t need = 2 * sz_wT + 2 * sz_x + (size_t)NROWS * 4 + (size_t)KDIM * 4;

  if (ws_size >= need) {
    char* p = (char*)d_ws;
    unsigned short* whT = (unsigned short*)p; p += sz_wT;
    unsigned short* wlT = (unsigned short*)p; p += sz_wT;
    unsigned short* xh  = (unsigned short*)p; p += sz_x;
    unsigned short* xl  = (unsigned short*)p; p += sz_x;
    float* x2 = (float*)p; p += (size_t)NROWS * 4;
    float* w2 = (float*)p;

    hipMemsetAsync(w2, 0, (size_t)KDIM * 4, stream);
    k_wconv<<<dim3(KDIM / 64, CDIM / 64), 256, 0, stream>>>(w, whT, wlT, w2);
    k_xconv<<<(NROWS * CDIM) / 1024, 256, 0, stream>>>(x, xh, xl);
    k_x2<<<NROWS, 64, 0, stream>>>(x, x2);
    k_gemm<<<dim3(NROWS / 256, KDIM / 128), 512, 0, stream>>>(xh, xl, whT, wlT, x2, w2, out);
  } else {
    k_fb<<<dim3(NROWS / 64, KDIM / 64), 256, 0, stream>>>(x, w, out);
  }
  k_row<<<NROWS, 256, 0, stream>>>(out, stdp);
}

// Round 3
// 326.007 us; speedup vs baseline: 2.2542x; 2.0097x over previous
//
#include <hip/hip_runtime.h>
#include <stdint.h>

#define NROWS 1024
#define CDIM  4096
#define KDIM  16384
#define SIDE  128

typedef __attribute__((ext_vector_type(8))) short short8;
typedef __attribute__((ext_vector_type(4))) float f32x4;

static __device__ __forceinline__ unsigned short f2bf(float f) {
  unsigned u = __float_as_uint(f);
  u += 0x7fffu + ((u >> 16) & 1u);   // round-to-nearest-even
  return (unsigned short)(u >> 16);
}
static __device__ __forceinline__ float bf2f(unsigned short h) {
  return __uint_as_float(((unsigned)h) << 16);
}

#define GLOAD_LDS16(g, l)                                                     \
  __builtin_amdgcn_global_load_lds(                                           \
      (const __attribute__((address_space(1))) void*)(g),                     \
      (__attribute__((address_space(3))) void*)(l), 16, 0, 0)

// 128B-row XOR-swizzle: 16B-chunk bits [6:4] ^= row bits [9:7] (row&7).
// Bank-quad = chunk ^ (row&7): 16 consecutive rows at a fixed logical chunk
// spread over all 8 quads, 2 lanes each (2-way = free, m136). Involution;
// preserves 16B alignment and row index.
#define SWZ(o) ((o) ^ (((o) >> 3) & 0x70))

// ---------- weights: f32 [c][k] -> bf16 hi/lo transposed [k][c]; fused w2 ----
__global__ __launch_bounds__(256) void k_wconv(const float* __restrict__ w,
                                               unsigned short* __restrict__ whT,
                                               unsigned short* __restrict__ wlT,
                                               float* __restrict__ w2) {
  __shared__ float T[64][65];
  const int k0 = blockIdx.x * 64, c0 = blockIdx.y * 64;
  const int t = threadIdx.x;
#pragma unroll
  for (int i = 0; i < 4; i++) {
    int e = i * 1024 + t * 4;
    int cr = e >> 6, kc = e & 63;
    float4 v = *(const float4*)(w + (size_t)(c0 + cr) * KDIM + k0 + kc);
    T[cr][kc] = v.x; T[cr][kc + 1] = v.y; T[cr][kc + 2] = v.z; T[cr][kc + 3] = v.w;
  }
  __syncthreads();
#pragma unroll
  for (int i = 0; i < 4; i++) {
    int e = i * 1024 + t * 4;
    int kr = e >> 6, cc = e & 63;
    ushort4 hv, lv;
    float f0 = T[cc + 0][kr], f1 = T[cc + 1][kr];
    float f2 = T[cc + 2][kr], f3 = T[cc + 3][kr];
    hv.x = f2bf(f0); lv.x = f2bf(f0 - bf2f(hv.x));
    hv.y = f2bf(f1); lv.y = f2bf(f1 - bf2f(hv.y));
    hv.z = f2bf(f2); lv.z = f2bf(f2 - bf2f(hv.z));
    hv.w = f2bf(f3); lv.w = f2bf(f3 - bf2f(hv.w));
    size_t off = (size_t)(k0 + kr) * CDIM + c0 + cc;
    *(ushort4*)(whT + off) = hv;
    *(ushort4*)(wlT + off) = lv;
    // fused w2: threads with the same kr are 16 consecutive lanes
    float s = f0 * f0 + f1 * f1 + f2 * f2 + f3 * f3;
#pragma unroll
    for (int off2 = 8; off2 > 0; off2 >>= 1) s += __shfl_down(s, off2);
    if ((t & 15) == 0) atomicAdd(&w2[k0 + kr], s);
  }
}

// ---------- x: f32 [n][c] -> bf16 hi (single) ----------
__global__ __launch_bounds__(256) void k_xconv(const float* __restrict__ x,
                                               unsigned short* __restrict__ xh) {
  size_t i = ((size_t)blockIdx.x * 256 + threadIdx.x) * 4;
  float4 v = *(const float4*)(x + i);
  ushort4 hv;
  hv.x = f2bf(v.x); hv.y = f2bf(v.y); hv.z = f2bf(v.z); hv.w = f2bf(v.w);
  *(ushort4*)(xh + i) = hv;
}

// ---------- x2[n] = sum_c x^2 ----------
__global__ void k_x2(const float* __restrict__ x, float* __restrict__ x2) {
  const int n = blockIdx.x, l = threadIdx.x;  // 64 threads
  const float* row = x + (size_t)n * CDIM;
  float s = 0.f;
#pragma unroll 4
  for (int i = 0; i < 16; i++) {
    float4 v = *(const float4*)(row + (i * 64 + l) * 4);
    s += v.x * v.x + v.y * v.y + v.z * v.z + v.w * v.w;
  }
#pragma unroll
  for (int off = 32; off > 0; off >>= 1) s += __shfl_down(s, off);
  if (l == 0) x2[n] = s;
}

// ---------- main MFMA GEMM (single bf16): approx norms2 -> out ----------
// BM=256, BN=128, BK=64; 512 threads = 8 waves as 4(M) x 2(N);
// per-wave 64x64 output = acc[4][4] of 16x16x32 fragments, 1 MFMA per (m,n,h).
__global__ __launch_bounds__(512, 2) void k_gemm(
    const unsigned short* __restrict__ xh,
    const unsigned short* __restrict__ whT,
    const float* __restrict__ x2, const float* __restrict__ w2,
    float* __restrict__ out) {
  __shared__ alignas(128) char smem[49152];
  char* const Ah = smem;            // 32 KB: 256 rows x 128B
  char* const Bh = smem + 32768;    // 16 KB: 128 rows x 128B
  const int t = threadIdx.x;
  const int m0 = blockIdx.x * 256, n0 = blockIdx.y * 128;
  const int lane = t & 63, wid = t >> 6;
  const int wr = (wid >> 1) * 64;   // wave row quadrant: 0,64,128,192
  const int wc = (wid & 1) * 64;    // wave col half: 0,64

  // staging geometry (rule #21): linear LDS dest chunk o_lin holds logical
  // chunk SWZ(o_lin) -> fetch that chunk's global data into it.
  int rowA[4], cbA[4];
  uint32_t loffA[4];
#pragma unroll
  for (int i = 0; i < 4; i++) {
    int o_lin = (i * 512 + t) * 16;
    int o_log = SWZ(o_lin);
    rowA[i] = o_log >> 7;
    cbA[i] = (o_log & 127) >> 1;
    loffA[i] = i * 8192 + wid * 1024;  // wave-uniform LDS base
  }
  int rowB[2], cbB[2];
  uint32_t loffB[2];
#pragma unroll
  for (int i = 0; i < 2; i++) {
    int o_lin = (i * 512 + t) * 16;
    int o_log = SWZ(o_lin);
    rowB[i] = o_log >> 7;
    cbB[i] = (o_log & 127) >> 1;
    loffB[i] = i * 8192 + wid * 1024;
  }

  f32x4 acc[4][4];
#pragma unroll
  for (int m = 0; m < 4; m++)
#pragma unroll
    for (int n = 0; n < 4; n++) acc[m][n] = (f32x4){0.f, 0.f, 0.f, 0.f};

  const int rlo = lane & 15;
  const int kgb = (lane >> 4) * 16;  // k-group byte offset within a K=32 half

  for (int c0 = 0; c0 < CDIM; c0 += 64) {
#pragma unroll
    for (int i = 0; i < 4; i++) {
      size_t ga = (size_t)(m0 + rowA[i]) * CDIM + c0 + cbA[i];
      GLOAD_LDS16(xh + ga, Ah + loffA[i]);
    }
#pragma unroll
    for (int i = 0; i < 2; i++) {
      size_t gb = (size_t)(n0 + rowB[i]) * CDIM + c0 + cbB[i];
      GLOAD_LDS16(whT + gb, Bh + loffB[i]);
    }
    __syncthreads();  // drains vmcnt before s_barrier

#pragma unroll
    for (int h = 0; h < 2; h++) {
      const int cby = h * 64 + kgb;
      short8 b_f[4];
#pragma unroll
      for (int n = 0; n < 4; n++)
        b_f[n] = *(const short8*)(Bh + SWZ((wc + n * 16 + rlo) * 128 + cby));
#pragma unroll
      for (int m = 0; m < 4; m++) {
        short8 ah = *(const short8*)(Ah + SWZ((wr + m * 16 + rlo) * 128 + cby));
#pragma unroll
        for (int n = 0; n < 4; n++)
          acc[m][n] = __builtin_amdgcn_mfma_f32_16x16x32_bf16(ah, b_f[n], acc[m][n], 0, 0, 0);
      }
    }
    __syncthreads();
  }

  // epilogue: norms2 ~= max(x2 + w2 - 2*xw, 0)
  float w2v[4];
#pragma unroll
  for (int n = 0; n < 4; n++) w2v[n] = w2[n0 + wc + n * 16 + rlo];
#pragma unroll
  for (int m = 0; m < 4; m++) {
#pragma unroll
    for (int j = 0; j < 4; j++) {
      int row = m0 + wr + m * 16 + (lane >> 4) * 4 + j;
      float xr = x2[row];
      float* orow = out + (size_t)row * KDIM;
#pragma unroll
      for (int n = 0; n < 4; n++) {
        int col = n0 + wc + n * 16 + rlo;
        float v = xr + w2v[n] - 2.0f * acc[m][n][j];
        orow[col] = v < 0.f ? 0.f : v;
      }
    }
  }
}

// ---------- fallback fp32 GEMM (exact), used only if ws too small ----------
__global__ __launch_bounds__(256) void k_fb(const float* __restrict__ x,
                                            const float* __restrict__ w,
                                            float* __restrict__ out) {
  __shared__ float xs[16][65];
  __shared__ float wsm[16][65];
  const int t = threadIdx.x;
  const int n0 = blockIdx.x * 64, k0 = blockIdx.y * 64;
  const int tx = t & 15, ty = t >> 4;
  float acc[4][4];
#pragma unroll
  for (int a = 0; a < 4; a++)
#pragma unroll
    for (int b = 0; b < 4; b++) acc[a][b] = 0.f;
  for (int c0 = 0; c0 < CDIM; c0 += 16) {
#pragma unroll
    for (int i = 0; i < 4; i++) {
      int e = i * 256 + t;
      int nl = e >> 4, cl = e & 15;
      xs[cl][nl] = x[(size_t)(n0 + nl) * CDIM + c0 + cl];
    }
#pragma unroll
    for (int i = 0; i < 4; i++) {
      int e = i * 256 + t;
      int cl = e >> 6, kl = e & 63;
      wsm[cl][kl] = w[(size_t)(c0 + cl) * KDIM + k0 + kl];
    }
    __syncthreads();
#pragma unroll
    for (int c = 0; c < 16; c++)
#pragma unroll
      for (int a = 0; a < 4; a++) {
        float xa = xs[c][ty * 4 + a];
#pragma unroll
        for (int b = 0; b < 4; b++) {
          float d = wsm[c][tx * 4 + b] - xa;
          acc[a][b] += d * d;
        }
      }
    __syncthreads();
  }
#pragma unroll
  for (int a = 0; a < 4; a++)
#pragma unroll
    for (int b = 0; b < 4; b++)
      out[(size_t)(n0 + ty * 4 + a) * KDIM + k0 + tx * 4 + b] = acc[a][b];
}

// ---------- per-row: min -> candidates -> exact refine -> RBF scale ----------
__global__ __launch_bounds__(256) void k_row(
    float* __restrict__ out, const float* __restrict__ stdp,
    const float* __restrict__ x, const unsigned short* __restrict__ whT,
    const unsigned short* __restrict__ wlT, const float* __restrict__ w2) {
  const int n = blockIdx.x, t = threadIdx.x;
  __shared__ alignas(16) float er[SIDE];
  __shared__ alignas(16) float ec[SIDE];
  __shared__ float rv[4];
  __shared__ float s_red[4];
  __shared__ int cand[128];
  __shared__ int s_ncand;
  __shared__ int s_bmu;
  __shared__ float s_inv;
  float* row = out + (size_t)n * KDIM;

  // pass 1: block-min of approximate scores
  float bv = 3.4e38f;
#pragma unroll 4
  for (int i = 0; i < 16; i++) {
    float4 v = *(const float4*)(row + (t + i * 256) * 4);
    bv = fminf(fminf(fminf(bv, v.x), fminf(v.y, v.z)), v.w);
  }
#pragma unroll
  for (int off = 32; off > 0; off >>= 1) bv = fminf(bv, __shfl_down(bv, off));
  if ((t & 63) == 0) rv[t >> 6] = bv;
  if (t == 0) s_ncand = 0;
  __syncthreads();
  const float thr = fminf(fminf(rv[0], rv[1]), fminf(rv[2], rv[3])) + 0.05f;

  // pass 2: collect candidate indices within the safety window
#pragma unroll 4
  for (int i = 0; i < 16; i++) {
    int k = (t + i * 256) * 4;
    float4 v = *(const float4*)(row + k);
    if (v.x <= thr) { int j = atomicAdd(&s_ncand, 1); if (j < 128) cand[j] = k; }
    if (v.y <= thr) { int j = atomicAdd(&s_ncand, 1); if (j < 128) cand[j] = k + 1; }
    if (v.z <= thr) { int j = atomicAdd(&s_ncand, 1); if (j < 128) cand[j] = k + 2; }
    if (v.w <= thr) { int j = atomicAdd(&s_ncand, 1); if (j < 128) cand[j] = k + 3; }
  }
  __syncthreads();
  int nc = s_ncand < 128 ? s_ncand : 128;

  // refine: exact score = w2[k] - 2 * dot(x_f32, wh+wl) per candidate
  float best = 3.4e38f;
  int bestk = 0x7fffffff;
  const float* xr = x + (size_t)n * CDIM;
  for (int j = 0; j < nc; j++) {
    const int k = cand[j];
    const unsigned short* wh = whT + (size_t)k * CDIM;
    const unsigned short* wl = wlT + (size_t)k * CDIM;
    float s = 0.f;
#pragma unroll
    for (int ii = 0; ii < 2; ii++) {
      int c = (ii * 256 + t) * 8;
      short8 h8 = *(const short8*)(wh + c);
      short8 l8 = *(const short8*)(wl + c);
      float4 xa = *(const float4*)(xr + c);
      float4 xb = *(const float4*)(xr + c + 4);
      s += xa.x * (bf2f((unsigned short)h8[0]) + bf2f((unsigned short)l8[0]));
      s += xa.y * (bf2f((unsigned short)h8[1]) + bf2f((unsigned short)l8[1]));
      s += xa.z * (bf2f((unsigned short)h8[2]) + bf2f((unsigned short)l8[2]));
      s += xa.w * (bf2f((unsigned short)h8[3]) + bf2f((unsigned short)l8[3]));
      s += xb.x * (bf2f((unsigned short)h8[4]) + bf2f((unsigned short)l8[4]));
      s += xb.y * (bf2f((unsigned short)h8[5]) + bf2f((unsigned short)l8[5]));
      s += xb.z * (bf2f((unsigned short)h8[6]) + bf2f((unsigned short)l8[6]));
      s += xb.w * (bf2f((unsigned short)h8[7]) + bf2f((unsigned short)l8[7]));
    }
#pragma unroll
    for (int off = 32; off > 0; off >>= 1) s += __shfl_down(s, off);
    if ((t & 63) == 0) s_red[t >> 6] = s;
    __syncthreads();
    if (t == 0) {
      float dot = s_red[0] + s_red[1] + s_red[2] + s_red[3];
      float sc = w2[k] - 2.0f * dot;
      if (sc < best || (sc == best && k < bestk)) { best = sc; bestk = k; }
    }
    __syncthreads();
  }
  if (t == 0) s_bmu = bestk;
  __syncthreads();

  const int bmu = s_bmu;
  const float sd = stdp[0];
  const float inv2s2 = -0.5f / (sd * sd);
  const float rr = (float)(bmu >> 7), ccol = (float)(bmu & 127);
  if (t < 128) {
    float d = (float)t - rr;
    er[t] = expf(d * d * inv2s2);
  } else {
    int j = t - 128;
    float d = (float)j - ccol;
    ec[j] = expf(d * d * inv2s2);
  }
  __syncthreads();
  if (t == 0) {
    float Sr = 0.f, Sc = 0.f;
    for (int i = 0; i < SIDE; i++) { Sr += er[i]; Sc += ec[i]; }
    s_inv = 1.0f / (Sr * Sc);
  }
  __syncthreads();
  const float inv = s_inv;
#pragma unroll 4
  for (int i = 0; i < 16; i++) {
    int k = (t + i * 256) * 4;
    float4 v = *(const float4*)(row + k);
    float e_r = er[k >> 7] * inv;
    const float4 e4 = *(const float4*)(&ec[k & 127]);
    v.x *= e_r * e4.x;
    v.y *= e_r * e4.y;
    v.z *= e_r * e4.z;
    v.w *= e_r * e4.w;
    *(float4*)(row + k) = v;
  }
}

// ---------- fallback per-row (no refinement; exact norms2 from k_fb) --------
__global__ __launch_bounds__(256) void k_row_fb(float* __restrict__ out,
                                                const float* __restrict__ stdp) {
  const int n = blockIdx.x, t = threadIdx.x;
  __shared__ alignas(16) float er[SIDE];
  __shared__ alignas(16) float ec[SIDE];
  __shared__ float rv[4];
  __shared__ int ri[4];
  __shared__ float s_inv;
  __shared__ int s_bmu;
  float* row = out + (size_t)n * KDIM;

  float bv = 3.4e38f;
  int bi = 0;
#pragma unroll 4
  for (int i = 0; i < 16; i++) {
    int k = (t + i * 256) * 4;
    float4 v = *(const float4*)(row + k);
    if (v.x < bv) { bv = v.x; bi = k; }
    if (v.y < bv) { bv = v.y; bi = k + 1; }
    if (v.z < bv) { bv = v.z; bi = k + 2; }
    if (v.w < bv) { bv = v.w; bi = k + 3; }
  }
#pragma unroll
  for (int off = 32; off > 0; off >>= 1) {
    float ov = __shfl_down(bv, off);
    int oi = __shfl_down(bi, off);
    if (ov < bv || (ov == bv && oi < bi)) { bv = ov; bi = oi; }
  }
  if ((t & 63) == 0) { rv[t >> 6] = bv; ri[t >> 6] = bi; }
  __syncthreads();
  if (t == 0) {
    for (int i = 1; i < 4; i++)
      if (rv[i] < bv || (rv[i] == bv && ri[i] < bi)) { bv = rv[i]; bi = ri[i]; }
    s_bmu = bi;
  }
  __syncthreads();
  const int bmu = s_bmu;
  const float sd = stdp[0];
  const float inv2s2 = -0.5f / (sd * sd);
  const float rr = (float)(bmu >> 7), ccol = (float)(bmu & 127);
  if (t < 128) {
    float d = (float)t - rr;
    er[t] = expf(d * d * inv2s2);
  } else {
    int j = t - 128;
    float d = (float)j - ccol;
    ec[j] = expf(d * d * inv2s2);
  }
  __syncthreads();
  if (t == 0) {
    float Sr = 0.f, Sc = 0.f;
    for (int i = 0; i < SIDE; i++) { Sr += er[i]; Sc += ec[i]; }
    s_inv = 1.0f / (Sr * Sc);
  }
  __syncthreads();
  const float inv = s_inv;
#pragma unroll 4
  for (int i = 0; i < 16; i++) {
    int k = (t + i * 256) * 4;
    float4 v = *(const float4*)(row + k);
    float e_r = er[k >> 7] * inv;
    const float4 e4 = *(const float4*)(&ec[k & 127]);
    v.x *= e_r * e4.x;
    v.y *= e_r * e4.y;
    v.z *= e_r * e4.z;
    v.w *= e_r * e4.w;
    *(float4*)(row + k) = v;
  }
}

extern "C" void kernel_launch(void* const* d_in, const int* in_sizes, int n_in,
                              void* d_out, int out_size, void* d_ws, size_t ws_size,
                              hipStream_t stream) {
  (void)in_sizes; (void)n_in; (void)out_size;
  const float* x = (const float*)d_in[0];
  const float* w = (const float*)d_in[1];
  const float* stdp = (const float*)d_in[2];
  float* out = (float*)d_out;

  const size_t sz_wT = (size_t)KDIM * CDIM * sizeof(unsigned short);  // 128 MiB each
  const size_t sz_x  = (size_t)NROWS * CDIM * sizeof(unsigned short); // 8 MiB
  const size_t need = 2 * sz_wT + sz_x + (size_t)NROWS * 4 + (size_t)KDIM * 4;

  if (ws_size >= need) {
    char* p = (char*)d_ws;
    unsigned short* whT = (unsigned short*)p; p += sz_wT;
    unsigned short* wlT = (unsigned short*)p; p += sz_wT;
    unsigned short* xh  = (unsigned short*)p; p += sz_x;
    float* x2 = (float*)p; p += (size_t)NROWS * 4;
    float* w2 = (float*)p;

    hipMemsetAsync(w2, 0, (size_t)KDIM * 4, stream);
    k_wconv<<<dim3(KDIM / 64, CDIM / 64), 256, 0, stream>>>(w, whT, wlT, w2);
    k_xconv<<<(NROWS * CDIM) / 1024, 256, 0, stream>>>(x, xh);
    k_x2<<<NROWS, 64, 0, stream>>>(x, x2);
    k_gemm<<<dim3(NROWS / 256, KDIM / 128), 512, 0, stream>>>(xh, whT, x2, w2, out);
    k_row<<<NROWS, 256, 0, stream>>>(out, stdp, x, whT, wlT, w2);
  } else {
    k_fb<<<dim3(NROWS / 64, KDIM / 64), 256, 0, stream>>>(x, w, out);
    k_row_fb<<<NROWS, 256, 0, stream>>>(out, stdp);
  }
}

// Round 4
// 307.757 us; speedup vs baseline: 2.3878x; 1.0593x over previous
//
#include <hip/hip_runtime.h>
#include <stdint.h>

#define NROWS 1024
#define CDIM  4096
#define KDIM  16384
#define SIDE  128

typedef __attribute__((ext_vector_type(8))) short short8;
typedef __attribute__((ext_vector_type(4))) float f32x4;

static __device__ __forceinline__ unsigned short f2bf(float f) {
  unsigned u = __float_as_uint(f);
  u += 0x7fffu + ((u >> 16) & 1u);   // round-to-nearest-even
  return (unsigned short)(u >> 16);
}
static __device__ __forceinline__ float bf2f(unsigned short h) {
  return __uint_as_float(((unsigned)h) << 16);
}

#define GLOAD_LDS16(g, l)                                                     \
  __builtin_amdgcn_global_load_lds(                                           \
      (const __attribute__((address_space(1))) void*)(g),                     \
      (__attribute__((address_space(3))) void*)(l), 16, 0, 0)

// 128B-row XOR-swizzle: 16B-chunk bits [6:4] ^= row bits [9:7] (row&7).
// Bank-quad = chunk ^ (row&7): 16 consecutive rows at a fixed logical chunk
// spread over all 8 quads, 2 lanes each (2-way = free, m136). Involution;
// preserves 16B alignment and row index.
#define SWZ(o) ((o) ^ (((o) >> 3) & 0x70))

// ---------- zero w2 (replaces pathological hipMemsetAsync fill) ----------
__global__ void k_zero(float* __restrict__ w2) {
  w2[blockIdx.x * 256 + threadIdx.x] = 0.f;
}

// ---------- weights: f32 [c][k] -> bf16 hi/lo transposed [k][c]; fused w2 ----
__global__ __launch_bounds__(256) void k_wconv(const float* __restrict__ w,
                                               unsigned short* __restrict__ whT,
                                               unsigned short* __restrict__ wlT,
                                               float* __restrict__ w2) {
  __shared__ float T[64][65];
  const int k0 = blockIdx.x * 64, c0 = blockIdx.y * 64;
  const int t = threadIdx.x;
#pragma unroll
  for (int i = 0; i < 4; i++) {
    int e = i * 1024 + t * 4;
    int cr = e >> 6, kc = e & 63;
    float4 v = *(const float4*)(w + (size_t)(c0 + cr) * KDIM + k0 + kc);
    T[cr][kc] = v.x; T[cr][kc + 1] = v.y; T[cr][kc + 2] = v.z; T[cr][kc + 3] = v.w;
  }
  __syncthreads();
#pragma unroll
  for (int i = 0; i < 4; i++) {
    int e = i * 1024 + t * 4;
    int kr = e >> 6, cc = e & 63;
    ushort4 hv, lv;
    float f0 = T[cc + 0][kr], f1 = T[cc + 1][kr];
    float f2 = T[cc + 2][kr], f3 = T[cc + 3][kr];
    hv.x = f2bf(f0); lv.x = f2bf(f0 - bf2f(hv.x));
    hv.y = f2bf(f1); lv.y = f2bf(f1 - bf2f(hv.y));
    hv.z = f2bf(f2); lv.z = f2bf(f2 - bf2f(hv.z));
    hv.w = f2bf(f3); lv.w = f2bf(f3 - bf2f(hv.w));
    size_t off = (size_t)(k0 + kr) * CDIM + c0 + cc;
    *(ushort4*)(whT + off) = hv;
    *(ushort4*)(wlT + off) = lv;
    // fused w2: threads with the same kr are 16 consecutive lanes
    float s = f0 * f0 + f1 * f1 + f2 * f2 + f3 * f3;
#pragma unroll
    for (int off2 = 8; off2 > 0; off2 >>= 1) s += __shfl_down(s, off2);
    if ((t & 15) == 0) atomicAdd(&w2[k0 + kr], s);
  }
}

// ---------- x: f32 [n][c] -> bf16 hi (single) ----------
__global__ __launch_bounds__(256) void k_xconv(const float* __restrict__ x,
                                               unsigned short* __restrict__ xh) {
  size_t i = ((size_t)blockIdx.x * 256 + threadIdx.x) * 4;
  float4 v = *(const float4*)(x + i);
  ushort4 hv;
  hv.x = f2bf(v.x); hv.y = f2bf(v.y); hv.z = f2bf(v.z); hv.w = f2bf(v.w);
  *(ushort4*)(xh + i) = hv;
}

// ---------- x2[n] = sum_c x^2 ----------
__global__ void k_x2(const float* __restrict__ x, float* __restrict__ x2) {
  const int n = blockIdx.x, l = threadIdx.x;  // 64 threads
  const float* row = x + (size_t)n * CDIM;
  float s = 0.f;
#pragma unroll 4
  for (int i = 0; i < 16; i++) {
    float4 v = *(const float4*)(row + (i * 64 + l) * 4);
    s += v.x * v.x + v.y * v.y + v.z * v.z + v.w * v.w;
  }
#pragma unroll
  for (int off = 32; off > 0; off >>= 1) s += __shfl_down(s, off);
  if (l == 0) x2[n] = s;
}

// ---------- main MFMA GEMM (single bf16): approx norms2 -> out ----------
// BM=256, BN=128, BK=64; 512 threads = 8 waves as 4(M) x 2(N);
// per-wave 64x64 output = acc[4][4] of 16x16x32 fragments.
// 1-D grid of 512 with XCD-aware swizzle (T1): the 4 M-chunks of one K-panel
// run consecutively on the same XCD -> whT panel hits that XCD's L2 3x.
__global__ __launch_bounds__(512, 2) void k_gemm(
    const unsigned short* __restrict__ xh,
    const unsigned short* __restrict__ whT,
    const float* __restrict__ x2, const float* __restrict__ w2,
    float* __restrict__ out) {
  __shared__ alignas(128) char smem[49152];
  char* const Ah = smem;            // 32 KB: 256 rows x 128B
  char* const Bh = smem + 32768;    // 16 KB: 128 rows x 128B
  const int t = threadIdx.x;
  // XCD swizzle: nwg=512, 512%8==0 -> simple bijective form.
  const int b = blockIdx.x;
  const int wg = (b & 7) * 64 + (b >> 3);
  const int m0 = (wg & 3) * 256, n0 = (wg >> 2) * 128;
  const int lane = t & 63, wid = t >> 6;
  const int wr = (wid >> 1) * 64;   // wave row quadrant: 0,64,128,192
  const int wc = (wid & 1) * 64;    // wave col half: 0,64

  // staging geometry (rule #21): linear LDS dest chunk o_lin holds logical
  // chunk SWZ(o_lin) -> fetch that chunk's global data into it.
  int rowA[4], cbA[4];
  uint32_t loffA[4];
#pragma unroll
  for (int i = 0; i < 4; i++) {
    int o_lin = (i * 512 + t) * 16;
    int o_log = SWZ(o_lin);
    rowA[i] = o_log >> 7;
    cbA[i] = (o_log & 127) >> 1;
    loffA[i] = i * 8192 + wid * 1024;  // wave-uniform LDS base
  }
  int rowB[2], cbB[2];
  uint32_t loffB[2];
#pragma unroll
  for (int i = 0; i < 2; i++) {
    int o_lin = (i * 512 + t) * 16;
    int o_log = SWZ(o_lin);
    rowB[i] = o_log >> 7;
    cbB[i] = (o_log & 127) >> 1;
    loffB[i] = i * 8192 + wid * 1024;
  }

  f32x4 acc[4][4];
#pragma unroll
  for (int m = 0; m < 4; m++)
#pragma unroll
    for (int n = 0; n < 4; n++) acc[m][n] = (f32x4){0.f, 0.f, 0.f, 0.f};

  const int rlo = lane & 15;
  const int kgb = (lane >> 4) * 16;  // k-group byte offset within a K=32 half

  for (int c0 = 0; c0 < CDIM; c0 += 64) {
#pragma unroll
    for (int i = 0; i < 4; i++) {
      size_t ga = (size_t)(m0 + rowA[i]) * CDIM + c0 + cbA[i];
      GLOAD_LDS16(xh + ga, Ah + loffA[i]);
    }
#pragma unroll
    for (int i = 0; i < 2; i++) {
      size_t gb = (size_t)(n0 + rowB[i]) * CDIM + c0 + cbB[i];
      GLOAD_LDS16(whT + gb, Bh + loffB[i]);
    }
    __syncthreads();  // drains vmcnt before s_barrier

#pragma unroll
    for (int h = 0; h < 2; h++) {
      const int cby = h * 64 + kgb;
      short8 b_f[4];
#pragma unroll
      for (int n = 0; n < 4; n++)
        b_f[n] = *(const short8*)(Bh + SWZ((wc + n * 16 + rlo) * 128 + cby));
#pragma unroll
      for (int m = 0; m < 4; m++) {
        short8 ah = *(const short8*)(Ah + SWZ((wr + m * 16 + rlo) * 128 + cby));
#pragma unroll
        for (int n = 0; n < 4; n++)
          acc[m][n] = __builtin_amdgcn_mfma_f32_16x16x32_bf16(ah, b_f[n], acc[m][n], 0, 0, 0);
      }
    }
    __syncthreads();
  }

  // epilogue: norms2 ~= max(x2 + w2 - 2*xw, 0)
  float w2v[4];
#pragma unroll
  for (int n = 0; n < 4; n++) w2v[n] = w2[n0 + wc + n * 16 + rlo];
#pragma unroll
  for (int m = 0; m < 4; m++) {
#pragma unroll
    for (int j = 0; j < 4; j++) {
      int row = m0 + wr + m * 16 + (lane >> 4) * 4 + j;
      float xr = x2[row];
      float* orow = out + (size_t)row * KDIM;
#pragma unroll
      for (int n = 0; n < 4; n++) {
        int col = n0 + wc + n * 16 + rlo;
        float v = xr + w2v[n] - 2.0f * acc[m][n][j];
        orow[col] = v < 0.f ? 0.f : v;
      }
    }
  }
}

// ---------- fallback fp32 GEMM (exact), used only if ws too small ----------
__global__ __launch_bounds__(256) void k_fb(const float* __restrict__ x,
                                            const float* __restrict__ w,
                                            float* __restrict__ out) {
  __shared__ float xs[16][65];
  __shared__ float wsm[16][65];
  const int t = threadIdx.x;
  const int n0 = blockIdx.x * 64, k0 = blockIdx.y * 64;
  const int tx = t & 15, ty = t >> 4;
  float acc[4][4];
#pragma unroll
  for (int a = 0; a < 4; a++)
#pragma unroll
    for (int b = 0; b < 4; b++) acc[a][b] = 0.f;
  for (int c0 = 0; c0 < CDIM; c0 += 16) {
#pragma unroll
    for (int i = 0; i < 4; i++) {
      int e = i * 256 + t;
      int nl = e >> 4, cl = e & 15;
      xs[cl][nl] = x[(size_t)(n0 + nl) * CDIM + c0 + cl];
    }
#pragma unroll
    for (int i = 0; i < 4; i++) {
      int e = i * 256 + t;
      int cl = e >> 6, kl = e & 63;
      wsm[cl][kl] = w[(size_t)(c0 + cl) * KDIM + k0 + kl];
    }
    __syncthreads();
#pragma unroll
    for (int c = 0; c < 16; c++)
#pragma unroll
      for (int a = 0; a < 4; a++) {
        float xa = xs[c][ty * 4 + a];
#pragma unroll
        for (int b = 0; b < 4; b++) {
          float d = wsm[c][tx * 4 + b] - xa;
          acc[a][b] += d * d;
        }
      }
    __syncthreads();
  }
#pragma unroll
  for (int a = 0; a < 4; a++)
#pragma unroll
    for (int b = 0; b < 4; b++)
      out[(size_t)(n0 + ty * 4 + a) * KDIM + k0 + tx * 4 + b] = acc[a][b];
}

// ---------- per-row: min -> candidates -> exact refine -> RBF scale ----------
__global__ __launch_bounds__(256) void k_row(
    float* __restrict__ out, const float* __restrict__ stdp,
    const float* __restrict__ x, const unsigned short* __restrict__ whT,
    const unsigned short* __restrict__ wlT, const float* __restrict__ w2) {
  const int n = blockIdx.x, t = threadIdx.x;
  __shared__ alignas(16) float er[SIDE];
  __shared__ alignas(16) float ec[SIDE];
  __shared__ float rv[4];
  __shared__ float s_red[4];
  __shared__ int cand[128];
  __shared__ int s_ncand;
  __shared__ int s_bmu;
  __shared__ float s_inv;
  float* row = out + (size_t)n * KDIM;

  // pass 1: block-min of approximate scores
  float bv = 3.4e38f;
#pragma unroll 4
  for (int i = 0; i < 16; i++) {
    float4 v = *(const float4*)(row + (t + i * 256) * 4);
    bv = fminf(fminf(fminf(bv, v.x), fminf(v.y, v.z)), v.w);
  }
#pragma unroll
  for (int off = 32; off > 0; off >>= 1) bv = fminf(bv, __shfl_down(bv, off));
  if ((t & 63) == 0) rv[t >> 6] = bv;
  if (t == 0) s_ncand = 0;
  __syncthreads();
  const float thr = fminf(fminf(rv[0], rv[1]), fminf(rv[2], rv[3])) + 0.05f;

  // pass 2: collect candidate indices within the safety window
#pragma unroll 4
  for (int i = 0; i < 16; i++) {
    int k = (t + i * 256) * 4;
    float4 v = *(const float4*)(row + k);
    if (v.x <= thr) { int j = atomicAdd(&s_ncand, 1); if (j < 128) cand[j] = k; }
    if (v.y <= thr) { int j = atomicAdd(&s_ncand, 1); if (j < 128) cand[j] = k + 1; }
    if (v.z <= thr) { int j = atomicAdd(&s_ncand, 1); if (j < 128) cand[j] = k + 2; }
    if (v.w <= thr) { int j = atomicAdd(&s_ncand, 1); if (j < 128) cand[j] = k + 3; }
  }
  __syncthreads();
  int nc = s_ncand < 128 ? s_ncand : 128;

  // refine: exact score = w2[k] - 2 * dot(x_f32, wh+wl) per candidate
  float best = 3.4e38f;
  int bestk = 0x7fffffff;
  const float* xr = x + (size_t)n * CDIM;
  for (int j = 0; j < nc; j++) {
    const int k = cand[j];
    const unsigned short* wh = whT + (size_t)k * CDIM;
    const unsigned short* wl = wlT + (size_t)k * CDIM;
    float s = 0.f;
#pragma unroll
    for (int ii = 0; ii < 2; ii++) {
      int c = (ii * 256 + t) * 8;
      short8 h8 = *(const short8*)(wh + c);
      short8 l8 = *(const short8*)(wl + c);
      float4 xa = *(const float4*)(xr + c);
      float4 xb = *(const float4*)(xr + c + 4);
      s += xa.x * (bf2f((unsigned short)h8[0]) + bf2f((unsigned short)l8[0]));
      s += xa.y * (bf2f((unsigned short)h8[1]) + bf2f((unsigned short)l8[1]));
      s += xa.z * (bf2f((unsigned short)h8[2]) + bf2f((unsigned short)l8[2]));
      s += xa.w * (bf2f((unsigned short)h8[3]) + bf2f((unsigned short)l8[3]));
      s += xb.x * (bf2f((unsigned short)h8[4]) + bf2f((unsigned short)l8[4]));
      s += xb.y * (bf2f((unsigned short)h8[5]) + bf2f((unsigned short)l8[5]));
      s += xb.z * (bf2f((unsigned short)h8[6]) + bf2f((unsigned short)l8[6]));
      s += xb.w * (bf2f((unsigned short)h8[7]) + bf2f((unsigned short)l8[7]));
    }
#pragma unroll
    for (int off = 32; off > 0; off >>= 1) s += __shfl_down(s, off);
    if ((t & 63) == 0) s_red[t >> 6] = s;
    __syncthreads();
    if (t == 0) {
      float dot = s_red[0] + s_red[1] + s_red[2] + s_red[3];
      float sc = w2[k] - 2.0f * dot;
      if (sc < best || (sc == best && k < bestk)) { best = sc; bestk = k; }
    }
    __syncthreads();
  }
  if (t == 0) s_bmu = bestk;
  __syncthreads();

  const int bmu = s_bmu;
  const float sd = stdp[0];
  const float inv2s2 = -0.5f / (sd * sd);
  const float rr = (float)(bmu >> 7), ccol = (float)(bmu & 127);
  if (t < 128) {
    float d = (float)t - rr;
    er[t] = expf(d * d * inv2s2);
  } else {
    int j = t - 128;
    float d = (float)j - ccol;
    ec[j] = expf(d * d * inv2s2);
  }
  __syncthreads();
  if (t == 0) {
    float Sr = 0.f, Sc = 0.f;
    for (int i = 0; i < SIDE; i++) { Sr += er[i]; Sc += ec[i]; }
    s_inv = 1.0f / (Sr * Sc);
  }
  __syncthreads();
  const float inv = s_inv;
#pragma unroll 4
  for (int i = 0; i < 16; i++) {
    int k = (t + i * 256) * 4;
    float4 v = *(const float4*)(row + k);
    float e_r = er[k >> 7] * inv;
    const float4 e4 = *(const float4*)(&ec[k & 127]);
    v.x *= e_r * e4.x;
    v.y *= e_r * e4.y;
    v.z *= e_r * e4.z;
    v.w *= e_r * e4.w;
    *(float4*)(row + k) = v;
  }
}

// ---------- fallback per-row (no refinement; exact norms2 from k_fb) --------
__global__ __launch_bounds__(256) void k_row_fb(float* __restrict__ out,
                                                const float* __restrict__ stdp) {
  const int n = blockIdx.x, t = threadIdx.x;
  __shared__ alignas(16) float er[SIDE];
  __shared__ alignas(16) float ec[SIDE];
  __shared__ float rv[4];
  __shared__ int ri[4];
  __shared__ float s_inv;
  __shared__ int s_bmu;
  float* row = out + (size_t)n * KDIM;

  float bv = 3.4e38f;
  int bi = 0;
#pragma unroll 4
  for (int i = 0; i < 16; i++) {
    int k = (t + i * 256) * 4;
    float4 v = *(const float4*)(row + k);
    if (v.x < bv) { bv = v.x; bi = k; }
    if (v.y < bv) { bv = v.y; bi = k + 1; }
    if (v.z < bv) { bv = v.z; bi = k + 2; }
    if (v.w < bv) { bv = v.w; bi = k + 3; }
  }
#pragma unroll
  for (int off = 32; off > 0; off >>= 1) {
    float ov = __shfl_down(bv, off);
    int oi = __shfl_down(bi, off);
    if (ov < bv || (ov == bv && oi < bi)) { bv = ov; bi = oi; }
  }
  if ((t & 63) == 0) { rv[t >> 6] = bv; ri[t >> 6] = bi; }
  __syncthreads();
  if (t == 0) {
    for (int i = 1; i < 4; i++)
      if (rv[i] < bv || (rv[i] == bv && ri[i] < bi)) { bv = rv[i]; bi = ri[i]; }
    s_bmu = bi;
  }
  __syncthreads();
  const int bmu = s_bmu;
  const float sd = stdp[0];
  const float inv2s2 = -0.5f / (sd * sd);
  const float rr = (float)(bmu >> 7), ccol = (float)(bmu & 127);
  if (t < 128) {
    float d = (float)t - rr;
    er[t] = expf(d * d * inv2s2);
  } else {
    int j = t - 128;
    float d = (float)j - ccol;
    ec[j] = expf(d * d * inv2s2);
  }
  __syncthreads();
  if (t == 0) {
    float Sr = 0.f, Sc = 0.f;
    for (int i = 0; i < SIDE; i++) { Sr += er[i]; Sc += ec[i]; }
    s_inv = 1.0f / (Sr * Sc);
  }
  __syncthreads();
  const float inv = s_inv;
#pragma unroll 4
  for (int i = 0; i < 16; i++) {
    int k = (t + i * 256) * 4;
    float4 v = *(const float4*)(row + k);
    float e_r = er[k >> 7] * inv;
    const float4 e4 = *(const float4*)(&ec[k & 127]);
    v.x *= e_r * e4.x;
    v.y *= e_r * e4.y;
    v.z *= e_r * e4.z;
    v.w *= e_r * e4.w;
    *(float4*)(row + k) = v;
  }
}

extern "C" void kernel_launch(void* const* d_in, const int* in_sizes, int n_in,
                              void* d_out, int out_size, void* d_ws, size_t ws_size,
                              hipStream_t stream) {
  (void)in_sizes; (void)n_in; (void)out_size;
  const float* x = (const float*)d_in[0];
  const float* w = (const float*)d_in[1];
  const float* stdp = (const float*)d_in[2];
  float* out = (float*)d_out;

  const size_t sz_wT = (size_t)KDIM * CDIM * sizeof(unsigned short);  // 128 MiB each
  const size_t sz_x  = (size_t)NROWS * CDIM * sizeof(unsigned short); // 8 MiB
  const size_t need = 2 * sz_wT + sz_x + (size_t)NROWS * 4 + (size_t)KDIM * 4;

  if (ws_size >= need) {
    char* p = (char*)d_ws;
    unsigned short* whT = (unsigned short*)p; p += sz_wT;
    unsigned short* wlT = (unsigned short*)p; p += sz_wT;
    unsigned short* xh  = (unsigned short*)p; p += sz_x;
    float* x2 = (float*)p; p += (size_t)NROWS * 4;
    float* w2 = (float*)p;

    k_zero<<<KDIM / 256, 256, 0, stream>>>(w2);
    k_wconv<<<dim3(KDIM / 64, CDIM / 64), 256, 0, stream>>>(w, whT, wlT, w2);
    k_xconv<<<(NROWS * CDIM) / 1024, 256, 0, stream>>>(x, xh);
    k_x2<<<NROWS, 64, 0, stream>>>(x, x2);
    k_gemm<<<512, 512, 0, stream>>>(xh, whT, x2, w2, out);
    k_row<<<NROWS, 256, 0, stream>>>(out, stdp, x, whT, wlT, w2);
  } else {
    k_fb<<<dim3(NROWS / 64, KDIM / 64), 256, 0, stream>>>(x, w, out);
    k_row_fb<<<NROWS, 256, 0, stream>>>(out, stdp);
  }
}

// Round 5
// 293.194 us; speedup vs baseline: 2.5065x; 1.0497x over previous
//
#include <hip/hip_runtime.h>
#include <stdint.h>

#define NROWS 1024
#define CDIM  4096
#define KDIM  16384
#define SIDE  128

typedef __attribute__((ext_vector_type(8))) short short8;
typedef __attribute__((ext_vector_type(4))) float f32x4;

static __device__ __forceinline__ unsigned short f2bf(float f) {
  unsigned u = __float_as_uint(f);
  u += 0x7fffu + ((u >> 16) & 1u);   // round-to-nearest-even
  return (unsigned short)(u >> 16);
}
static __device__ __forceinline__ float bf2f(unsigned short h) {
  return __uint_as_float(((unsigned)h) << 16);
}

#define GLOAD_LDS16(g, l)                                                     \
  __builtin_amdgcn_global_load_lds(                                           \
      (const __attribute__((address_space(1))) void*)(g),                     \
      (__attribute__((address_space(3))) void*)(l), 16, 0, 0)

// 128B-row XOR-swizzle: 16B-chunk bits [6:4] ^= row bits [9:7] (row&7).
// Bank-quad = chunk ^ (row&7): perfectly uniform for the 16-row x 4-kgroup
// wave read pattern (proven 0 conflicts in R3/R4). Involution; 16B-aligned.
#define SWZ(o) ((o) ^ (((o) >> 3) & 0x70))

// ---------- zero w2 ----------
__global__ void k_zero(float* __restrict__ w2) {
  w2[blockIdx.x * 256 + threadIdx.x] = 0.f;
}

// ---------- weights: f32 [c][k] -> bf16 hi/lo transposed [k][c]; fused w2 ----
__global__ __launch_bounds__(256) void k_wconv(const float* __restrict__ w,
                                               unsigned short* __restrict__ whT,
                                               unsigned short* __restrict__ wlT,
                                               float* __restrict__ w2) {
  __shared__ float T[64][65];
  const int k0 = blockIdx.x * 64, c0 = blockIdx.y * 64;
  const int t = threadIdx.x;
#pragma unroll
  for (int i = 0; i < 4; i++) {
    int e = i * 1024 + t * 4;
    int cr = e >> 6, kc = e & 63;
    float4 v = *(const float4*)(w + (size_t)(c0 + cr) * KDIM + k0 + kc);
    T[cr][kc] = v.x; T[cr][kc + 1] = v.y; T[cr][kc + 2] = v.z; T[cr][kc + 3] = v.w;
  }
  __syncthreads();
#pragma unroll
  for (int i = 0; i < 4; i++) {
    int e = i * 1024 + t * 4;
    int kr = e >> 6, cc = e & 63;
    ushort4 hv, lv;
    float f0 = T[cc + 0][kr], f1 = T[cc + 1][kr];
    float f2 = T[cc + 2][kr], f3 = T[cc + 3][kr];
    hv.x = f2bf(f0); lv.x = f2bf(f0 - bf2f(hv.x));
    hv.y = f2bf(f1); lv.y = f2bf(f1 - bf2f(hv.y));
    hv.z = f2bf(f2); lv.z = f2bf(f2 - bf2f(hv.z));
    hv.w = f2bf(f3); lv.w = f2bf(f3 - bf2f(hv.w));
    size_t off = (size_t)(k0 + kr) * CDIM + c0 + cc;
    *(ushort4*)(whT + off) = hv;
    *(ushort4*)(wlT + off) = lv;
    float s = f0 * f0 + f1 * f1 + f2 * f2 + f3 * f3;
#pragma unroll
    for (int off2 = 8; off2 > 0; off2 >>= 1) s += __shfl_down(s, off2);
    if ((t & 15) == 0) atomicAdd(&w2[k0 + kr], s);
  }
}

// ---------- x: f32 [n][c] -> bf16 ----------
__global__ __launch_bounds__(256) void k_xconv(const float* __restrict__ x,
                                               unsigned short* __restrict__ xh) {
  size_t i = ((size_t)blockIdx.x * 256 + threadIdx.x) * 4;
  float4 v = *(const float4*)(x + i);
  ushort4 hv;
  hv.x = f2bf(v.x); hv.y = f2bf(v.y); hv.z = f2bf(v.z); hv.w = f2bf(v.w);
  *(ushort4*)(xh + i) = hv;
}

// ---------- x2[n] = sum_c x^2 ----------
__global__ void k_x2(const float* __restrict__ x, float* __restrict__ x2) {
  const int n = blockIdx.x, l = threadIdx.x;  // 64 threads
  const float* row = x + (size_t)n * CDIM;
  float s = 0.f;
#pragma unroll 4
  for (int i = 0; i < 16; i++) {
    float4 v = *(const float4*)(row + (i * 64 + l) * 4);
    s += v.x * v.x + v.y * v.y + v.z * v.z + v.w * v.w;
  }
#pragma unroll
  for (int off = 32; off > 0; off >>= 1) s += __shfl_down(s, off);
  if (l == 0) x2[n] = s;
}

// ---------- main MFMA GEMM: BM=BN=256, BK=64, 8 waves (2M x 4N) ----------
// Per-wave 128x64 output (acc[8][4]); K-tile double-buffered 128 KB LDS;
// counted vmcnt(8) pipeline (T4), raw s_barrier, setprio (T5), SWZ (T2),
// XCD-chunked block mapping (T1): XCD x owns n-panels [8x,8x+8) x all 4 m.
__global__ __launch_bounds__(512, 2) void k_gemm(
    const unsigned short* __restrict__ xh,
    const unsigned short* __restrict__ whT,
    const float* __restrict__ x2, const float* __restrict__ w2,
    float* __restrict__ out) {
  extern __shared__ char smem[];  // 131072 B: buf d -> A at d*65536, B at +32768
  const int t = threadIdx.x;
  const int b = blockIdx.x;
  const int L = (b & 7) * 32 + (b >> 3);   // 256 wgs, bijective
  const int m0 = (L & 3) * 256, n0 = (L >> 2) * 256;
  const int lane = t & 63, wid = t >> 6;
  const int wrow = (wid >> 2) * 128;   // wave M-half: 0 or 128
  const int wcol = (wid & 3) * 64;     // wave N-quarter: 0,64,128,192

  // staging geometry (rule #21): linear LDS chunk o_lin holds logical
  // chunk SWZ(o_lin); 4 loads/thread cover one 256x64 bf16 tile (32 KB).
  int rowS[4], cbS[4];
  uint32_t loffS[4];
#pragma unroll
  for (int i = 0; i < 4; i++) {
    int o_lin = (i * 512 + t) * 16;
    int o_log = SWZ(o_lin);
    rowS[i] = o_log >> 7;          // 0..255
    cbS[i] = (o_log & 127) >> 1;   // element col 0..63
    loffS[i] = i * 8192 + wid * 1024;  // wave-uniform LDS base (linear dest)
  }

  f32x4 acc[8][4];
#pragma unroll
  for (int m = 0; m < 8; m++)
#pragma unroll
    for (int n = 0; n < 4; n++) acc[m][n] = (f32x4){0.f, 0.f, 0.f, 0.f};

  const int rlo = lane & 15;
  const int kgb = (lane >> 4) * 16;  // k-group byte offset within a K=32 slice

#define STAGE_TILE(tt, d)                                                     \
  {                                                                           \
    const int c0s = (tt) * 64;                                                \
    char* const dst = smem + (d) * 65536;                                     \
    _Pragma("unroll")                                                         \
    for (int i = 0; i < 4; i++) {                                             \
      size_t ga = (size_t)(m0 + rowS[i]) * CDIM + c0s + cbS[i];               \
      GLOAD_LDS16(xh + ga, dst + loffS[i]);                                   \
    }                                                                         \
    _Pragma("unroll")                                                         \
    for (int i = 0; i < 4; i++) {                                             \
      size_t gb = (size_t)(n0 + rowS[i]) * CDIM + c0s + cbS[i];               \
      GLOAD_LDS16(whT + gb, dst + 32768 + loffS[i]);                          \
    }                                                                         \
  }

  STAGE_TILE(0, 0);  // prologue: 8 loads in flight

  for (int tl = 0; tl < 64; ++tl) {
    const int cur = tl & 1;
    if (tl < 63) {
      STAGE_TILE(tl + 1, cur ^ 1);  // 8 more loads; never drain to 0 (T4)
      asm volatile("s_waitcnt vmcnt(8)" ::: "memory");  // tile tl landed
    } else {
      asm volatile("s_waitcnt vmcnt(0)" ::: "memory");
    }
    asm volatile("s_barrier" ::: "memory");  // all waves' loads landed

    const char* const Ab = smem + cur * 65536;
    const char* const Bb = Ab + 32768;
    short8 b_f[4][2];
#pragma unroll
    for (int n = 0; n < 4; n++)
#pragma unroll
      for (int ks = 0; ks < 2; ks++)
        b_f[n][ks] = *(const short8*)(Bb + SWZ((wcol + n * 16 + rlo) * 128 + ks * 64 + kgb));
    __builtin_amdgcn_s_setprio(1);
#pragma unroll
    for (int m = 0; m < 8; m++) {
      const char* ar = Ab + (wrow + m * 16 + rlo) * 128;
      short8 a0 = *(const short8*)(Ab + SWZ((wrow + m * 16 + rlo) * 128 + kgb));
      short8 a1 = *(const short8*)(Ab + SWZ((wrow + m * 16 + rlo) * 128 + 64 + kgb));
      (void)ar;
#pragma unroll
      for (int n = 0; n < 4; n++) {
        acc[m][n] = __builtin_amdgcn_mfma_f32_16x16x32_bf16(a0, b_f[n][0], acc[m][n], 0, 0, 0);
        acc[m][n] = __builtin_amdgcn_mfma_f32_16x16x32_bf16(a1, b_f[n][1], acc[m][n], 0, 0, 0);
      }
    }
    __builtin_amdgcn_s_setprio(0);
    asm volatile("s_barrier" ::: "memory");  // reads done; buf reusable
  }
#undef STAGE_TILE

  // epilogue: norms2 ~= max(x2 + w2 - 2*xw, 0)
  float w2v[4];
#pragma unroll
  for (int n = 0; n < 4; n++) w2v[n] = w2[n0 + wcol + n * 16 + rlo];
#pragma unroll
  for (int m = 0; m < 8; m++) {
#pragma unroll
    for (int j = 0; j < 4; j++) {
      int row = m0 + wrow + m * 16 + (lane >> 4) * 4 + j;
      float xr = x2[row];
      float* orow = out + (size_t)row * KDIM;
#pragma unroll
      for (int n = 0; n < 4; n++) {
        int col = n0 + wcol + n * 16 + rlo;
        float v = xr + w2v[n] - 2.0f * acc[m][n][j];
        orow[col] = v < 0.f ? 0.f : v;
      }
    }
  }
}

// ---------- fallback fp32 GEMM (exact), used only if ws too small ----------
__global__ __launch_bounds__(256) void k_fb(const float* __restrict__ x,
                                            const float* __restrict__ w,
                                            float* __restrict__ out) {
  __shared__ float xs[16][65];
  __shared__ float wsm[16][65];
  const int t = threadIdx.x;
  const int n0 = blockIdx.x * 64, k0 = blockIdx.y * 64;
  const int tx = t & 15, ty = t >> 4;
  float acc[4][4];
#pragma unroll
  for (int a = 0; a < 4; a++)
#pragma unroll
    for (int b = 0; b < 4; b++) acc[a][b] = 0.f;
  for (int c0 = 0; c0 < CDIM; c0 += 16) {
#pragma unroll
    for (int i = 0; i < 4; i++) {
      int e = i * 256 + t;
      int nl = e >> 4, cl = e & 15;
      xs[cl][nl] = x[(size_t)(n0 + nl) * CDIM + c0 + cl];
    }
#pragma unroll
    for (int i = 0; i < 4; i++) {
      int e = i * 256 + t;
      int cl = e >> 6, kl = e & 63;
      wsm[cl][kl] = w[(size_t)(c0 + cl) * KDIM + k0 + kl];
    }
    __syncthreads();
#pragma unroll
    for (int c = 0; c < 16; c++)
#pragma unroll
      for (int a = 0; a < 4; a++) {
        float xa = xs[c][ty * 4 + a];
#pragma unroll
        for (int b = 0; b < 4; b++) {
          float d = wsm[c][tx * 4 + b] - xa;
          acc[a][b] += d * d;
        }
      }
    __syncthreads();
  }
#pragma unroll
  for (int a = 0; a < 4; a++)
#pragma unroll
    for (int b = 0; b < 4; b++)
      out[(size_t)(n0 + ty * 4 + a) * KDIM + k0 + tx * 4 + b] = acc[a][b];
}

// ---------- per-row: min -> candidates -> exact refine -> RBF scale ----------
__global__ __launch_bounds__(256) void k_row(
    float* __restrict__ out, const float* __restrict__ stdp,
    const float* __restrict__ x, const unsigned short* __restrict__ whT,
    const unsigned short* __restrict__ wlT, const float* __restrict__ w2) {
  const int n = blockIdx.x, t = threadIdx.x;
  __shared__ alignas(16) float er[SIDE];
  __shared__ alignas(16) float ec[SIDE];
  __shared__ float rv[4];
  __shared__ float s_red[4];
  __shared__ int cand[128];
  __shared__ int s_ncand;
  __shared__ int s_bmu;
  __shared__ float s_inv;
  float* row = out + (size_t)n * KDIM;

  // pass 1: block-min of approximate scores
  float bv = 3.4e38f;
#pragma unroll 4
  for (int i = 0; i < 16; i++) {
    float4 v = *(const float4*)(row + (t + i * 256) * 4);
    bv = fminf(fminf(fminf(bv, v.x), fminf(v.y, v.z)), v.w);
  }
#pragma unroll
  for (int off = 32; off > 0; off >>= 1) bv = fminf(bv, __shfl_down(bv, off));
  if ((t & 63) == 0) rv[t >> 6] = bv;
  if (t == 0) s_ncand = 0;
  __syncthreads();
  const float thr = fminf(fminf(rv[0], rv[1]), fminf(rv[2], rv[3])) + 0.05f;

  // pass 2: collect candidate indices within the safety window
#pragma unroll 4
  for (int i = 0; i < 16; i++) {
    int k = (t + i * 256) * 4;
    float4 v = *(const float4*)(row + k);
    if (v.x <= thr) { int j = atomicAdd(&s_ncand, 1); if (j < 128) cand[j] = k; }
    if (v.y <= thr) { int j = atomicAdd(&s_ncand, 1); if (j < 128) cand[j] = k + 1; }
    if (v.z <= thr) { int j = atomicAdd(&s_ncand, 1); if (j < 128) cand[j] = k + 2; }
    if (v.w <= thr) { int j = atomicAdd(&s_ncand, 1); if (j < 128) cand[j] = k + 3; }
  }
  __syncthreads();
  int nc = s_ncand < 128 ? s_ncand : 128;

  // refine: exact score = w2[k] - 2 * dot(x_f32, wh+wl) per candidate
  float best = 3.4e38f;
  int bestk = 0x7fffffff;
  const float* xr = x + (size_t)n * CDIM;
  for (int j = 0; j < nc; j++) {
    const int k = cand[j];
    const unsigned short* wh = whT + (size_t)k * CDIM;
    const unsigned short* wl = wlT + (size_t)k * CDIM;
    float s = 0.f;
#pragma unroll
    for (int ii = 0; ii < 2; ii++) {
      int c = (ii * 256 + t) * 8;
      short8 h8 = *(const short8*)(wh + c);
      short8 l8 = *(const short8*)(wl + c);
      float4 xa = *(const float4*)(xr + c);
      float4 xb = *(const float4*)(xr + c + 4);
      s += xa.x * (bf2f((unsigned short)h8[0]) + bf2f((unsigned short)l8[0]));
      s += xa.y * (bf2f((unsigned short)h8[1]) + bf2f((unsigned short)l8[1]));
      s += xa.z * (bf2f((unsigned short)h8[2]) + bf2f((unsigned short)l8[2]));
      s += xa.w * (bf2f((unsigned short)h8[3]) + bf2f((unsigned short)l8[3]));
      s += xb.x * (bf2f((unsigned short)h8[4]) + bf2f((unsigned short)l8[4]));
      s += xb.y * (bf2f((unsigned short)h8[5]) + bf2f((unsigned short)l8[5]));
      s += xb.z * (bf2f((unsigned short)h8[6]) + bf2f((unsigned short)l8[6]));
      s += xb.w * (bf2f((unsigned short)h8[7]) + bf2f((unsigned short)l8[7]));
    }
#pragma unroll
    for (int off = 32; off > 0; off >>= 1) s += __shfl_down(s, off);
    if ((t & 63) == 0) s_red[t >> 6] = s;
    __syncthreads();
    if (t == 0) {
      float dot = s_red[0] + s_red[1] + s_red[2] + s_red[3];
      float sc = w2[k] - 2.0f * dot;
      if (sc < best || (sc == best && k < bestk)) { best = sc; bestk = k; }
    }
    __syncthreads();
  }
  if (t == 0) s_bmu = bestk;
  __syncthreads();

  const int bmu = s_bmu;
  const float sd = stdp[0];
  const float inv2s2 = -0.5f / (sd * sd);
  const float rr = (float)(bmu >> 7), ccol = (float)(bmu & 127);
  if (t < 128) {
    float d = (float)t - rr;
    er[t] = expf(d * d * inv2s2);
  } else {
    int j = t - 128;
    float d = (float)j - ccol;
    ec[j] = expf(d * d * inv2s2);
  }
  __syncthreads();
  if (t == 0) {
    float Sr = 0.f, Sc = 0.f;
    for (int i = 0; i < SIDE; i++) { Sr += er[i]; Sc += ec[i]; }
    s_inv = 1.0f / (Sr * Sc);
  }
  __syncthreads();
  const float inv = s_inv;
#pragma unroll 4
  for (int i = 0; i < 16; i++) {
    int k = (t + i * 256) * 4;
    float4 v = *(const float4*)(row + k);
    float e_r = er[k >> 7] * inv;
    const float4 e4 = *(const float4*)(&ec[k & 127]);
    v.x *= e_r * e4.x;
    v.y *= e_r * e4.y;
    v.z *= e_r * e4.z;
    v.w *= e_r * e4.w;
    *(float4*)(row + k) = v;
  }
}

// ---------- fallback per-row (exact norms2 from k_fb) ----------
__global__ __launch_bounds__(256) void k_row_fb(float* __restrict__ out,
                                                const float* __restrict__ stdp) {
  const int n = blockIdx.x, t = threadIdx.x;
  __shared__ alignas(16) float er[SIDE];
  __shared__ alignas(16) float ec[SIDE];
  __shared__ float rv[4];
  __shared__ int ri[4];
  __shared__ float s_inv;
  __shared__ int s_bmu;
  float* row = out + (size_t)n * KDIM;

  float bv = 3.4e38f;
  int bi = 0;
#pragma unroll 4
  for (int i = 0; i < 16; i++) {
    int k = (t + i * 256) * 4;
    float4 v = *(const float4*)(row + k);
    if (v.x < bv) { bv = v.x; bi = k; }
    if (v.y < bv) { bv = v.y; bi = k + 1; }
    if (v.z < bv) { bv = v.z; bi = k + 2; }
    if (v.w < bv) { bv = v.w; bi = k + 3; }
  }
#pragma unroll
  for (int off = 32; off > 0; off >>= 1) {
    float ov = __shfl_down(bv, off);
    int oi = __shfl_down(bi, off);
    if (ov < bv || (ov == bv && oi < bi)) { bv = ov; bi = oi; }
  }
  if ((t & 63) == 0) { rv[t >> 6] = bv; ri[t >> 6] = bi; }
  __syncthreads();
  if (t == 0) {
    for (int i = 1; i < 4; i++)
      if (rv[i] < bv || (rv[i] == bv && ri[i] < bi)) { bv = rv[i]; bi = ri[i]; }
    s_bmu = bi;
  }
  __syncthreads();
  const int bmu = s_bmu;
  const float sd = stdp[0];
  const float inv2s2 = -0.5f / (sd * sd);
  const float rr = (float)(bmu >> 7), ccol = (float)(bmu & 127);
  if (t < 128) {
    float d = (float)t - rr;
    er[t] = expf(d * d * inv2s2);
  } else {
    int j = t - 128;
    float d = (float)j - ccol;
    ec[j] = expf(d * d * inv2s2);
  }
  __syncthreads();
  if (t == 0) {
    float Sr = 0.f, Sc = 0.f;
    for (int i = 0; i < SIDE; i++) { Sr += er[i]; Sc += ec[i]; }
    s_inv = 1.0f / (Sr * Sc);
  }
  __syncthreads();
  const float inv = s_inv;
#pragma unroll 4
  for (int i = 0; i < 16; i++) {
    int k = (t + i * 256) * 4;
    float4 v = *(const float4*)(row + k);
    float e_r = er[k >> 7] * inv;
    const float4 e4 = *(const float4*)(&ec[k & 127]);
    v.x *= e_r * e4.x;
    v.y *= e_r * e4.y;
    v.z *= e_r * e4.z;
    v.w *= e_r * e4.w;
    *(float4*)(row + k) = v;
  }
}

extern "C" void kernel_launch(void* const* d_in, const int* in_sizes, int n_in,
                              void* d_out, int out_size, void* d_ws, size_t ws_size,
                              hipStream_t stream) {
  (void)in_sizes; (void)n_in; (void)out_size;
  const float* x = (const float*)d_in[0];
  const float* w = (const float*)d_in[1];
  const float* stdp = (const float*)d_in[2];
  float* out = (float*)d_out;

  const size_t sz_wT = (size_t)KDIM * CDIM * sizeof(unsigned short);  // 128 MiB each
  const size_t sz_x  = (size_t)NROWS * CDIM * sizeof(unsigned short); // 8 MiB
  const size_t need = 2 * sz_wT + sz_x + (size_t)NROWS * 4 + (size_t)KDIM * 4;

  if (ws_size >= need) {
    char* p = (char*)d_ws;
    unsigned short* whT = (unsigned short*)p; p += sz_wT;
    unsigned short* wlT = (unsigned short*)p; p += sz_wT;
    unsigned short* xh  = (unsigned short*)p; p += sz_x;
    float* x2 = (float*)p; p += (size_t)NROWS * 4;
    float* w2 = (float*)p;

    // allow 128 KB dynamic LDS for k_gemm (host-side, idempotent, capture-safe)
    static int lds_ok = -1;
    if (lds_ok < 0)
      lds_ok = (int)hipFuncSetAttribute((const void*)k_gemm,
                                        hipFuncAttributeMaxDynamicSharedMemorySize,
                                        131072);

    k_zero<<<KDIM / 256, 256, 0, stream>>>(w2);
    k_wconv<<<dim3(KDIM / 64, CDIM / 64), 256, 0, stream>>>(w, whT, wlT, w2);
    k_xconv<<<(NROWS * CDIM) / 1024, 256, 0, stream>>>(x, xh);
    k_x2<<<NROWS, 64, 0, stream>>>(x, x2);
    k_gemm<<<256, 512, 131072, stream>>>(xh, whT, x2, w2, out);
    k_row<<<NROWS, 256, 0, stream>>>(out, stdp, x, whT, wlT, w2);
  } else {
    k_fb<<<dim3(NROWS / 64, KDIM / 64), 256, 0, stream>>>(x, w, out);
    k_row_fb<<<NROWS, 256, 0, stream>>>(out, stdp);
  }
}